// Round 1
// baseline (30.968 us; speedup 1.0000x reference)
//
#include <hip/hip_runtime.h>

#define GS 1000
#define NCP 16
#define XSTART -3.0f
#define XEND 3.0f

__global__ __launch_bounds__(256) void bspline_lut_kernel(
    const float* __restrict__ x,
    const float* __restrict__ cp,
    const float* __restrict__ bg,
    float* __restrict__ out,
    int n4)
{
    // Per-block scalar LUT: g[i] = dot(basis_grid[i], control_points)
    __shared__ float tbl[GS];
    for (int i = threadIdx.x; i < GS; i += 256) {
        const float* row = bg + i * NCP;
        float s = 0.0f;
        #pragma unroll
        for (int j = 0; j < NCP; ++j) s += row[j] * cp[j];
        tbl[i] = s;
    }
    __syncthreads();

    const float scale = (float)(GS - 1) / (XEND - XSTART);
    int idx = blockIdx.x * blockDim.x + threadIdx.x;
    int stride = gridDim.x * blockDim.x;

    for (int i = idx; i < n4; i += stride) {
        float4 v = reinterpret_cast<const float4*>(x)[i];
        float vv[4] = {v.x, v.y, v.z, v.w};
        float r[4];
        #pragma unroll
        for (int j = 0; j < 4; ++j) {
            float xc = fminf(fmaxf(vv[j], XSTART), XEND);
            float ind = (xc - XSTART) * scale;       // in [0, 999]
            int f = (int)ind;                         // floor (ind >= 0)
            f = min(f, GS - 1);
            int c = min(f + 1, GS - 1);
            float w = ind - (float)f;
            float gf = tbl[f];
            float gc = tbl[c];
            r[j] = gf + w * (gc - gf);
        }
        float4 o = make_float4(r[0], r[1], r[2], r[3]);
        reinterpret_cast<float4*>(out)[i] = o;
    }
}

extern "C" void kernel_launch(void* const* d_in, const int* in_sizes, int n_in,
                              void* d_out, int out_size, void* d_ws, size_t ws_size,
                              hipStream_t stream) {
    const float* x  = (const float*)d_in[0];
    const float* cp = (const float*)d_in[1];
    const float* bg = (const float*)d_in[2];
    float* out = (float*)d_out;

    int n = in_sizes[0];          // 16777216, divisible by 4
    int n4 = n / 4;

    int blocks = (n4 + 255) / 256;
    if (blocks > 2048) blocks = 2048;

    bspline_lut_kernel<<<blocks, 256, 0, stream>>>(x, cp, bg, out, n4);
}

// Round 2
// 30.645 us; speedup vs baseline: 1.0105x; 1.0105x over previous
//
#include <hip/hip_runtime.h>

#define GS 1000
#define NCP 16
#define XSTART -3.0f
#define XEND 3.0f

__device__ __forceinline__ float dot16(const float* __restrict__ row,
                                       float4 c0, float4 c1, float4 c2, float4 c3) {
    const float4* r4 = reinterpret_cast<const float4*>(row);
    float4 a0 = r4[0], a1 = r4[1], a2 = r4[2], a3 = r4[3];
    float s = a0.x * c0.x;
    s = fmaf(a0.y, c0.y, s); s = fmaf(a0.z, c0.z, s); s = fmaf(a0.w, c0.w, s);
    s = fmaf(a1.x, c1.x, s); s = fmaf(a1.y, c1.y, s); s = fmaf(a1.z, c1.z, s); s = fmaf(a1.w, c1.w, s);
    s = fmaf(a2.x, c2.x, s); s = fmaf(a2.y, c2.y, s); s = fmaf(a2.z, c2.z, s); s = fmaf(a2.w, c2.w, s);
    s = fmaf(a3.x, c3.x, s); s = fmaf(a3.y, c3.y, s); s = fmaf(a3.z, c3.z, s); s = fmaf(a3.w, c3.w, s);
    return s;
}

// Kernel 1 (tiny): pair table ws2[i] = (g[i], g[min(i+1,GS-1)]),
// g[i] = dot(basis_grid[i], control_points). 1000 float2 = 8 KB.
__global__ __launch_bounds__(256) void build_table_kernel(
    const float* __restrict__ cp,
    const float* __restrict__ bg,
    float2* __restrict__ ws2)
{
    int i = blockIdx.x * 256 + threadIdx.x;
    if (i >= GS) return;
    const float4* c4 = reinterpret_cast<const float4*>(cp);
    float4 c0 = c4[0], c1 = c4[1], c2 = c4[2], c3 = c4[3];
    int i1 = min(i + 1, GS - 1);
    float g0 = dot16(bg + i * NCP, c0, c1, c2, c3);
    float g1 = dot16(bg + i1 * NCP, c0, c1, c2, c3);
    ws2[i] = make_float2(g0, g1);
}

__device__ __forceinline__ float bspline_eval(float v, const float2* tbl, float scale) {
    float xc = fminf(fmaxf(v, XSTART), XEND);
    float ind = (xc - XSTART) * scale;      // in [0, 999]
    int f = (int)ind;
    f = min(f, GS - 1);
    float w = ind - (float)f;
    float2 p = tbl[f];                       // one ds_read_b64
    return fmaf(w, p.y - p.x, p.x);
}

// Kernel 2: streaming lerp through the LDS pair table.
__global__ __launch_bounds__(256) void bspline_main_kernel(
    const float* __restrict__ x,
    const float2* __restrict__ ws2,
    float* __restrict__ out,
    int n4)
{
    __shared__ float2 tbl[GS];
    {
        const float4* src = reinterpret_cast<const float4*>(ws2);
        float4* dst = reinterpret_cast<float4*>(tbl);
        for (int i = threadIdx.x; i < GS / 2; i += 256) dst[i] = src[i]; // 500 f4
    }
    __syncthreads();

    const float scale = (float)(GS - 1) / (XEND - XSTART);
    const float4* x4 = reinterpret_cast<const float4*>(x);
    float4* o4 = reinterpret_cast<float4*>(out);
    int idx = blockIdx.x * 256 + threadIdx.x;
    int stride = gridDim.x * 256;

    int i = idx;
    for (; i + stride < n4; i += 2 * stride) {
        float4 va = x4[i];
        float4 vb = x4[i + stride];
        float4 oa, ob;
        oa.x = bspline_eval(va.x, tbl, scale);
        oa.y = bspline_eval(va.y, tbl, scale);
        oa.z = bspline_eval(va.z, tbl, scale);
        oa.w = bspline_eval(va.w, tbl, scale);
        ob.x = bspline_eval(vb.x, tbl, scale);
        ob.y = bspline_eval(vb.y, tbl, scale);
        ob.z = bspline_eval(vb.z, tbl, scale);
        ob.w = bspline_eval(vb.w, tbl, scale);
        o4[i] = oa;
        o4[i + stride] = ob;
    }
    if (i < n4) {
        float4 va = x4[i];
        float4 oa;
        oa.x = bspline_eval(va.x, tbl, scale);
        oa.y = bspline_eval(va.y, tbl, scale);
        oa.z = bspline_eval(va.z, tbl, scale);
        oa.w = bspline_eval(va.w, tbl, scale);
        o4[i] = oa;
    }
}

// Fallback (round-1 single kernel) if ws_size is too small for the pair table.
__global__ __launch_bounds__(256) void bspline_lut_kernel(
    const float* __restrict__ x,
    const float* __restrict__ cp,
    const float* __restrict__ bg,
    float* __restrict__ out,
    int n4)
{
    __shared__ float tblس[1]; // placeholder to keep layout separate
    __shared__ float tbl[GS];
    for (int i = threadIdx.x; i < GS; i += 256) {
        const float* row = bg + i * NCP;
        float s = 0.0f;
        #pragma unroll
        for (int j = 0; j < NCP; ++j) s += row[j] * cp[j];
        tbl[i] = s;
    }
    __syncthreads();
    const float scale = (float)(GS - 1) / (XEND - XSTART);
    int idx = blockIdx.x * blockDim.x + threadIdx.x;
    int stride = gridDim.x * blockDim.x;
    for (int i = idx; i < n4; i += stride) {
        float4 v = reinterpret_cast<const float4*>(x)[i];
        float vv[4] = {v.x, v.y, v.z, v.w};
        float r[4];
        #pragma unroll
        for (int j = 0; j < 4; ++j) {
            float xc = fminf(fmaxf(vv[j], XSTART), XEND);
            float ind = (xc - XSTART) * scale;
            int f = (int)ind;
            f = min(f, GS - 1);
            int c = min(f + 1, GS - 1);
            float w = ind - (float)f;
            r[j] = tbl[f] + w * (tbl[c] - tbl[f]);
        }
        reinterpret_cast<float4*>(out)[i] = make_float4(r[0], r[1], r[2], r[3]);
    }
}

extern "C" void kernel_launch(void* const* d_in, const int* in_sizes, int n_in,
                              void* d_out, int out_size, void* d_ws, size_t ws_size,
                              hipStream_t stream) {
    const float* x  = (const float*)d_in[0];
    const float* cp = (const float*)d_in[1];
    const float* bg = (const float*)d_in[2];
    float* out = (float*)d_out;

    int n = in_sizes[0];          // 16777216, divisible by 4
    int n4 = n / 4;

    int blocks = (n4 + 255) / 256;
    if (blocks > 2048) blocks = 2048;

    if (ws_size >= GS * sizeof(float2)) {
        float2* ws2 = (float2*)d_ws;
        build_table_kernel<<<(GS + 255) / 256, 256, 0, stream>>>(cp, bg, ws2);
        bspline_main_kernel<<<blocks, 256, 0, stream>>>(x, ws2, out, n4);
    } else {
        bspline_lut_kernel<<<blocks, 256, 0, stream>>>(x, cp, bg, out, n4);
    }
}